// Round 4
// baseline (471.891 us; speedup 1.0000x reference)
//
#include <hip/hip_runtime.h>
#include <stdint.h>

// MultiResolutionHashEncoding: N points x 16 levels x 2 features.
// out[p, l*2+f] = tables[l, idx(l,p), f]
//   idx = python_mod(abs_int32((x*P1)^(y*P2)^(z*P3)), table_size[l])
//   (x,y,z) = floor(coord * res[l]) in fp32, cast int32.
//
// Resolutions derived analytically from floor(16 * g^l), g = 128^(1/15).
// Levels 0..14 have safe margins; level 15 is mathematically exactly 2048
// before fp64 rounding -> coin flip 2047/2048. Using 2048 this round.
// Table sizes: min(res^3, 2^19). Levels >=6 are 2^19 -> mask; 0..5 magic-mod.

#define TPB 256

__global__ __launch_bounds__(TPB) void hashenc_kernel(
    const float* __restrict__ coords,
    const float* __restrict__ tables,
    float* __restrict__ out,
    int npts)
{
    constexpr int RESI[16] = {16, 22, 30, 42, 58, 80, 111, 153,
                              212, 294, 406, 561, 776, 1072, 1482, 2048};
    constexpr int SIZ[16] = {4096, 10648, 27000, 74088, 195112, 512000,
                             524288, 524288, 524288, 524288, 524288,
                             524288, 524288, 524288, 524288, 524288};

    // stride-33 padding: write phase banks (t + j) % 32 -> conflict-free;
    // read phase 2-way aliasing only (free).
    __shared__ float buf[TPB * 33];

    const int t = threadIdx.x;
    const long long pbase = (long long)blockIdx.x * TPB;
    const long long p = pbase + t;

    // N is a multiple of 256 (2^21); no tail guard needed.
    const float cx = coords[3 * p + 0];
    const float cy = coords[3 * p + 1];
    const float cz = coords[3 * p + 2];

    float2 feat[16];
#pragma unroll
    for (int l = 0; l < 16; ++l) {
        const float rf = (float)RESI[l];
        const int x = (int)floorf(cx * rf);
        const int y = (int)floorf(cy * rf);
        const int z = (int)floorf(cz * rf);
        // int32 wraparound multiplies + xor (do in uint32, C UB-free)
        const uint32_t h = (uint32_t)x * 73856093u
                         ^ (uint32_t)y * 19349663u
                         ^ (uint32_t)z * 83492791u;
        const int32_t hs = (int32_t)h;
        uint32_t idx;
        if (SIZ[l] == (1 << 19)) {
            // numpy: abs(INT_MIN) = INT_MIN; python-mod by 2^19 == two's
            // complement mask.
            const uint32_t a = (hs < 0) ? (0u - h) : h;
            idx = a & 0x7FFFFu;
        } else {
            // abs with INT_MIN wrap, then python-sign modulo
            int32_t a = (hs < 0) ? (int32_t)(0u - h) : hs;
            int32_t r = a % SIZ[l];   // compile-time divisor -> magic mul
            if (r < 0) r += SIZ[l];
            idx = (uint32_t)r;
        }
        // tables laid out (16, 2^19, 2) f32, zero-padded per level
        feat[l] = *reinterpret_cast<const float2*>(
            tables + ((size_t)l << 20) + ((size_t)idx << 1));
    }

#pragma unroll
    for (int l = 0; l < 16; ++l) {
        buf[t * 33 + 2 * l + 0] = feat[l].x;
        buf[t * 33 + 2 * l + 1] = feat[l].y;
    }
    __syncthreads();

    // coalesced write: block owns out[pbase*32 .. pbase*32 + 8192)
    float* oblk = out + pbase * 32;
#pragma unroll
    for (int k = 0; k < 32; ++k) {
        const int f = k * TPB + t;
        const float v = buf[(f >> 5) * 33 + (f & 31)];
        // nontemporal: keep the 256MB output stream from evicting the
        // gather-hot hash tables out of L2/L3
        __builtin_nontemporal_store(v, &oblk[f]);
    }
}

extern "C" void kernel_launch(void* const* d_in, const int* in_sizes, int n_in,
                              void* d_out, int out_size, void* d_ws, size_t ws_size,
                              hipStream_t stream)
{
    const float* coords = (const float*)d_in[0];
    const float* tables = (const float*)d_in[1];
    float* out = (float*)d_out;
    const int npts = in_sizes[0] / 3;
    const int blocks = (npts + TPB - 1) / TPB;
    hipLaunchKernelGGL(hashenc_kernel, dim3(blocks), dim3(TPB), 0, stream,
                       coords, tables, out, npts);
}

// Round 6
// 464.186 us; speedup vs baseline: 1.0166x; 1.0166x over previous
//
#include <hip/hip_runtime.h>
#include <stdint.h>

// MultiResolutionHashEncoding: N points x 16 levels x 2 features.
// out[p, l*2+f] = tables[l, idx(l,p), f]
//   idx = python_mod(abs_int32((x*P1)^(y*P2)^(z*P3)), table_size[l])
//   (x,y,z) = floor(coord * res[l]) in fp32, cast int32.
//
// R4 verified: level-15 res = 2048, absmax 0.0, dur 477us.
// R4 counters: FETCH 1.59GB (random-gather line fill, L3-served),
//   WRITE 262MB (ideal), VALUBusy 5%, Occ 42% (LDS-capped 4 blk/CU).
// R5/R6: latency-bound theory -> halve LDS (two-half transpose, 16.9KB)
//   for 8 blk/CU occupancy; float4 stores via native vector type
//   (HIP float4 is a struct -> __builtin_nontemporal_store rejects it).

#define TPB 256

typedef float vfloat4 __attribute__((ext_vector_type(4)));

__global__ __launch_bounds__(TPB) void hashenc_kernel(
    const float* __restrict__ coords,
    const float* __restrict__ tables,
    float* __restrict__ out,
    int npts)
{
    constexpr int RESI[16] = {16, 22, 30, 42, 58, 80, 111, 153,
                              212, 294, 406, 561, 776, 1072, 1482, 2048};
    constexpr int SIZ[16] = {4096, 10648, 27000, 74088, 195112, 512000,
                             524288, 524288, 524288, 524288, 524288,
                             524288, 524288, 524288, 524288, 524288};

    // 128 points x 33-stride (pad) = 16896 B -> 8 blocks/CU (was 33.8KB/4).
    __shared__ float buf[128 * 33];

    const int t = threadIdx.x;
    const long long pbase = (long long)blockIdx.x * TPB;
    const long long p = pbase + t;

    // N = 2^21, multiple of 256: no tail guard.
    const float cx = coords[3 * p + 0];
    const float cy = coords[3 * p + 1];
    const float cz = coords[3 * p + 2];

    float2 feat[16];
#pragma unroll
    for (int l = 0; l < 16; ++l) {
        const float rf = (float)RESI[l];
        const int x = (int)floorf(cx * rf);
        const int y = (int)floorf(cy * rf);
        const int z = (int)floorf(cz * rf);
        // int32 wraparound multiplies + xor (uint32 = UB-free)
        const uint32_t h = (uint32_t)x * 73856093u
                         ^ (uint32_t)y * 19349663u
                         ^ (uint32_t)z * 83492791u;
        const int32_t hs = (int32_t)h;
        uint32_t idx;
        if (SIZ[l] == (1 << 19)) {
            // numpy abs(INT_MIN)=INT_MIN; python-mod 2^19 == mask
            const uint32_t a = (hs < 0) ? (0u - h) : h;
            idx = a & 0x7FFFFu;
        } else {
            int32_t a = (hs < 0) ? (int32_t)(0u - h) : hs;
            int32_t r = a % SIZ[l];   // compile-time divisor -> magic mul
            if (r < 0) r += SIZ[l];
            idx = (uint32_t)r;
        }
        feat[l] = *reinterpret_cast<const float2*>(
            tables + ((size_t)l << 20) + ((size_t)idx << 1));
    }

    // Two-half transpose: points [h*128, h*128+128) staged, then all 256
    // threads store 4096 floats as float4 (coalesced 1KB/wave-instr).
    float* oblk = out + pbase * 32;
#pragma unroll
    for (int h = 0; h < 2; ++h) {
        if ((t >> 7) == h) {
            const int r = t & 127;
#pragma unroll
            for (int l = 0; l < 16; ++l) {
                // banks (r + 2l) % 32: 64 lanes -> 2-way alias (free)
                buf[r * 33 + 2 * l + 0] = feat[l].x;
                buf[r * 33 + 2 * l + 1] = feat[l].y;
            }
        }
        __syncthreads();
#pragma unroll
        for (int k = 0; k < 4; ++k) {
            const int f = k * 1024 + t * 4;          // [0,4096)
            const int row = f >> 5;                   // 0..127
            const int col = f & 31;                   // (t&7)*4, float4-aligned
            const vfloat4 v = *reinterpret_cast<const vfloat4*>(&buf[row * 33 + col]);
            // nontemporal: keep 256MB output stream out of L2/L3 so the
            // gather-hot tables stay cached
            __builtin_nontemporal_store(v,
                reinterpret_cast<vfloat4*>(&oblk[(long long)h * 4096 + f]));
        }
        __syncthreads();
    }
}

extern "C" void kernel_launch(void* const* d_in, const int* in_sizes, int n_in,
                              void* d_out, int out_size, void* d_ws, size_t ws_size,
                              hipStream_t stream)
{
    const float* coords = (const float*)d_in[0];
    const float* tables = (const float*)d_in[1];
    float* out = (float*)d_out;
    const int npts = in_sizes[0] / 3;
    const int blocks = (npts + TPB - 1) / TPB;
    hipLaunchKernelGGL(hashenc_kernel, dim3(blocks), dim3(TPB), 0, stream,
                       coords, tables, out, npts);
}

// Round 7
// 441.984 us; speedup vs baseline: 1.0677x; 1.0502x over previous
//
#include <hip/hip_runtime.h>
#include <stdint.h>

// MultiResolutionHashEncoding — R7: two-phase level-phased gather.
//
// R4: correct (absmax 0.0), 477us. R6: occupancy 42->82%, dur unchanged
//   -> throughput-bound on FETCH (1.53GB/dispatch random line fills), not
//   latency-bound. Each fine-level 64B table line is hit ~30x/dispatch but
//   the 262MB write stream + fill churn evicts it from L3 between uses.
// R7 theory: level-phase the gathers so the active level's 4MB table is
//   per-XCD-L2-resident (4MB L2/XCD). Persistent grid (2048 blocks, all
//   resident) loops level-OUTER over its 1024-point stripe -> natural
//   phase alignment. ws[l][p] float2 writes are coalesced. Phase 2
//   transposes (L,N,2)->(N,32) as a pure streaming op (R6 LDS machinery).
// Diagnostic: phase-1 FETCH <= 0.3e6 KB => L2 capture worked.

#define TPB 256

typedef float vfloat4 __attribute__((ext_vector_type(4)));

__device__ __forceinline__ uint32_t hash_idx(float cx, float cy, float cz,
                                             int resi, int siz)
{
    const float rf = (float)resi;
    const int x = (int)floorf(cx * rf);
    const int y = (int)floorf(cy * rf);
    const int z = (int)floorf(cz * rf);
    // int32 wraparound multiplies + xor (uint32 = UB-free)
    const uint32_t h = (uint32_t)x * 73856093u
                     ^ (uint32_t)y * 19349663u
                     ^ (uint32_t)z * 83492791u;
    const int32_t hs = (int32_t)h;
    if (siz == (1 << 19)) {
        // numpy abs(INT_MIN)=INT_MIN; python-mod 2^19 == mask
        const uint32_t a = (hs < 0) ? (0u - h) : h;
        return a & 0x7FFFFu;
    } else {
        int32_t a = (hs < 0) ? (int32_t)(0u - h) : hs;
        int32_t r = a % siz;          // compile-time divisor -> magic mul
        if (r < 0) r += siz;
        return (uint32_t)r;
    }
}

#define RESI_LIST {16, 22, 30, 42, 58, 80, 111, 153, \
                   212, 294, 406, 561, 776, 1072, 1482, 2048}
#define SIZ_LIST  {4096, 10648, 27000, 74088, 195112, 512000, \
                   524288, 524288, 524288, 524288, 524288, \
                   524288, 524288, 524288, 524288, 524288}

// ---------------- Phase 1: level-phased gather -> ws (L, N, 2) -------------
// 2048 persistent blocks (8/CU, all resident), each owns 1024 points.
// Level OUTER: at any wall-clock instant all blocks gather from ~the same
// level -> its 4MB table is L2-resident per XCD.
__global__ __launch_bounds__(TPB) void hashenc_gather(
    const float* __restrict__ coords,
    const float* __restrict__ tables,
    float2* __restrict__ ws,
    int npts)
{
    constexpr int RESI[16] = RESI_LIST;
    constexpr int SIZ[16] = SIZ_LIST;

    const int t = threadIdx.x;
    const long long base = (long long)blockIdx.x * 1024;

    float cx[4], cy[4], cz[4];
#pragma unroll
    for (int j = 0; j < 4; ++j) {
        const long long p = base + j * 256 + t;
        cx[j] = coords[3 * p + 0];
        cy[j] = coords[3 * p + 1];
        cz[j] = coords[3 * p + 2];
    }

#pragma unroll
    for (int l = 0; l < 16; ++l) {
        const float* tab = tables + ((size_t)l << 20);
        float2 g[4];
#pragma unroll
        for (int j = 0; j < 4; ++j) {
            const uint32_t idx = hash_idx(cx[j], cy[j], cz[j], RESI[l], SIZ[l]);
            g[j] = *reinterpret_cast<const float2*>(tab + ((size_t)idx << 1));
        }
        float2* wl = ws + (size_t)l * npts + base;
#pragma unroll
        for (int j = 0; j < 4; ++j)
            wl[j * 256 + t] = g[j];   // coalesced 8B/lane; keep in L2/L3 for phase 2
    }
}

// ---------------- Phase 2: transpose ws (L,N,2) -> out (N, 32) -------------
__global__ __launch_bounds__(TPB) void hashenc_transpose(
    const float2* __restrict__ ws,
    float* __restrict__ out,
    int npts)
{
    __shared__ float buf[128 * 33];

    const int t = threadIdx.x;
    const long long pbase = (long long)blockIdx.x * TPB;
    const long long p = pbase + t;

    float2 feat[16];
#pragma unroll
    for (int l = 0; l < 16; ++l)
        feat[l] = ws[(size_t)l * npts + p];   // coalesced 8B/lane

    float* oblk = out + pbase * 32;
#pragma unroll
    for (int h = 0; h < 2; ++h) {
        if ((t >> 7) == h) {
            const int r = t & 127;
#pragma unroll
            for (int l = 0; l < 16; ++l) {
                buf[r * 33 + 2 * l + 0] = feat[l].x;
                buf[r * 33 + 2 * l + 1] = feat[l].y;
            }
        }
        __syncthreads();
#pragma unroll
        for (int k = 0; k < 4; ++k) {
            const int f = k * 1024 + t * 4;
            const int row = f >> 5;
            const int col = f & 31;
            const vfloat4 v = *reinterpret_cast<const vfloat4*>(&buf[row * 33 + col]);
            __builtin_nontemporal_store(v,
                reinterpret_cast<vfloat4*>(&oblk[(long long)h * 4096 + f]));
        }
        __syncthreads();
    }
}

// ---------------- Fallback: R6 single-phase (if ws too small) --------------
__global__ __launch_bounds__(TPB) void hashenc_kernel(
    const float* __restrict__ coords,
    const float* __restrict__ tables,
    float* __restrict__ out,
    int npts)
{
    constexpr int RESI[16] = RESI_LIST;
    constexpr int SIZ[16] = SIZ_LIST;

    __shared__ float buf[128 * 33];

    const int t = threadIdx.x;
    const long long pbase = (long long)blockIdx.x * TPB;
    const long long p = pbase + t;

    const float cx = coords[3 * p + 0];
    const float cy = coords[3 * p + 1];
    const float cz = coords[3 * p + 2];

    float2 feat[16];
#pragma unroll
    for (int l = 0; l < 16; ++l) {
        const uint32_t idx = hash_idx(cx, cy, cz, RESI[l], SIZ[l]);
        feat[l] = *reinterpret_cast<const float2*>(
            tables + ((size_t)l << 20) + ((size_t)idx << 1));
    }

    float* oblk = out + pbase * 32;
#pragma unroll
    for (int h = 0; h < 2; ++h) {
        if ((t >> 7) == h) {
            const int r = t & 127;
#pragma unroll
            for (int l = 0; l < 16; ++l) {
                buf[r * 33 + 2 * l + 0] = feat[l].x;
                buf[r * 33 + 2 * l + 1] = feat[l].y;
            }
        }
        __syncthreads();
#pragma unroll
        for (int k = 0; k < 4; ++k) {
            const int f = k * 1024 + t * 4;
            const int row = f >> 5;
            const int col = f & 31;
            const vfloat4 v = *reinterpret_cast<const vfloat4*>(&buf[row * 33 + col]);
            __builtin_nontemporal_store(v,
                reinterpret_cast<vfloat4*>(&oblk[(long long)h * 4096 + f]));
        }
        __syncthreads();
    }
}

extern "C" void kernel_launch(void* const* d_in, const int* in_sizes, int n_in,
                              void* d_out, int out_size, void* d_ws, size_t ws_size,
                              hipStream_t stream)
{
    const float* coords = (const float*)d_in[0];
    const float* tables = (const float*)d_in[1];
    float* out = (float*)d_out;
    const int npts = in_sizes[0] / 3;   // 2^21

    const size_t need = (size_t)16 * (size_t)npts * sizeof(float2);
    if (ws_size >= need && (npts % 1024) == 0) {
        hipLaunchKernelGGL(hashenc_gather, dim3(npts / 1024), dim3(TPB), 0, stream,
                           coords, tables, (float2*)d_ws, npts);
        hipLaunchKernelGGL(hashenc_transpose, dim3(npts / TPB), dim3(TPB), 0, stream,
                           (const float2*)d_ws, out, npts);
    } else {
        hipLaunchKernelGGL(hashenc_kernel, dim3(npts / TPB), dim3(TPB), 0, stream,
                           coords, tables, out, npts);
    }
}